// Round 10
// baseline (8659.295 us; speedup 1.0000x reference)
//
#include <hip/hip_runtime.h>
#include <hip/hip_fp16.h>
#include <hip/hip_cooperative_groups.h>

namespace cg = cooperative_groups;

// HyperScatteringModule: V=65536, E=16384, NNZ=1048576, F=128
#define FEAT 128

// ---------------- fp16 helpers ----------------

__device__ inline float hlo(unsigned u) {
    unsigned short s = (unsigned short)(u & 0xFFFFu);
    __half h = *(__half*)&s;
    return __half2float(h);
}
__device__ inline float hhi(unsigned u) {
    unsigned short s = (unsigned short)(u >> 16);
    __half h = *(__half*)&s;
    return __half2float(h);
}
__device__ inline unsigned hpack(float a, float b) {
    __half ha = __float2half_rn(a), hb = __float2half_rn(b);
    unsigned short ua = *(unsigned short*)&ha, ub = *(unsigned short*)&hb;
    return (unsigned)ua | ((unsigned)ub << 16);
}

// ---------------- fp8 e4m3 helpers ----------------
#if __has_builtin(__builtin_amdgcn_cvt_pk_f32_fp8) && __has_builtin(__builtin_amdgcn_cvt_pk_fp8_f32)
typedef float floatx2 __attribute__((ext_vector_type(2)));
__device__ inline void fp8x2_to_f32(unsigned lo16, float& a, float& b) {
    floatx2 r = __builtin_amdgcn_cvt_pk_f32_fp8((int)lo16, false);
    a = r.x;
    b = r.y;
}
__device__ inline unsigned f32_to_fp8x2(float a, float b) {
    return (unsigned)__builtin_amdgcn_cvt_pk_fp8_f32(a, b, 0, false) & 0xFFFFu;
}
#else
__device__ inline float fp8_dec1(unsigned u) {
    unsigned s = (u >> 7) & 1u, e = (u >> 3) & 15u, m = u & 7u;
    float v;
    if (e != 0) {
        unsigned bits = (s << 31) | ((e + 120u) << 23) | (m << 20);
        v = __uint_as_float(bits);
    } else {
        v = (float)m * 0.001953125f;
        if (s) v = -v;
    }
    return v;
}
__device__ inline void fp8x2_to_f32(unsigned lo16, float& a, float& b) {
    a = fp8_dec1(lo16 & 0xFFu);
    b = fp8_dec1((lo16 >> 8) & 0xFFu);
}
__device__ inline unsigned fp8_enc1(float x) {
    float ax = fabsf(x);
    unsigned s = (__float_as_uint(x) >> 31) << 7;
    if (ax >= 448.f) return s | 0x7Eu;
    if (ax < 0.0009765625f) return s;
    if (ax < 0.015625f) {
        unsigned m = (unsigned)__builtin_rintf(ax * 512.f);
        if (m > 7u) m = 7u;
        return s | m;
    }
    unsigned bits = __float_as_uint(ax);
    int e32 = (int)((bits >> 23) & 255u) - 127;
    unsigned mant = bits & 0x7FFFFFu;
    unsigned m3 = mant >> 20;
    unsigned rem = mant & 0xFFFFFu;
    if (rem > 0x80000u || (rem == 0x80000u && (m3 & 1u))) {
        m3++;
        if (m3 == 8u) { m3 = 0; e32++; }
    }
    if (e32 > 8) return s | 0x7Eu;
    return s | ((unsigned)(e32 + 7) << 3) | m3;
}
__device__ inline unsigned f32_to_fp8x2(float a, float b) {
    return fp8_enc1(a) | (fp8_enc1(b) << 8);
}
#endif

// ---------------- CSR build ----------------

__global__ void count_deg(const int* __restrict__ vids, const int* __restrict__ eids,
                          int* __restrict__ deg_v, int* __restrict__ deg_e,
                          int* __restrict__ deg_eb, int nnz) {
    int n = blockIdx.x * blockDim.x + threadIdx.x;
    if (n < nnz) {
        int v = vids[n], e = eids[n];
        atomicAdd(&deg_v[v], 1);
        atomicAdd(&deg_e[e], 1);
        atomicAdd(&deg_eb[e * 8 + (v >> 13)], 1);  // 8 vertex-buckets of 8192
    }
}

// Exclusive scan over CHUNK-padded degrees; off/cur = padded offsets, inv = 1/true_deg.
template <int N, int T, int CHUNK>
__global__ __launch_bounds__(T) void scan_pad(const int* __restrict__ deg,
                                              int* __restrict__ off,
                                              int* __restrict__ cur,
                                              float* __restrict__ inv) {
    __shared__ int partial[T];
    const int per = N / T;
    int tid = threadIdx.x;
    int base = tid * per;
    int dloc[per];
    int s = 0;
#pragma unroll
    for (int i = 0; i < per / 4; ++i) {
        int4 d4 = *(const int4*)(deg + base + 4 * i);
        dloc[4 * i] = d4.x; dloc[4 * i + 1] = d4.y;
        dloc[4 * i + 2] = d4.z; dloc[4 * i + 3] = d4.w;
        s += ((d4.x + CHUNK - 1) & ~(CHUNK - 1)) + ((d4.y + CHUNK - 1) & ~(CHUNK - 1)) +
             ((d4.z + CHUNK - 1) & ~(CHUNK - 1)) + ((d4.w + CHUNK - 1) & ~(CHUNK - 1));
    }
    partial[tid] = s;
    __syncthreads();
    for (int d = 1; d < T; d <<= 1) {
        int add = (tid >= d) ? partial[tid - d] : 0;
        __syncthreads();
        partial[tid] += add;
        __syncthreads();
    }
    int run = (tid > 0) ? partial[tid - 1] : 0;
#pragma unroll
    for (int i = 0; i < per / 4; ++i) {
        int o[4];
        float iv[4];
#pragma unroll
        for (int j = 0; j < 4; ++j) {
            int d = dloc[4 * i + j];
            o[j] = run;
            iv[j] = (d > 0) ? (1.0f / (float)d) : 0.0f;
            run += (d + CHUNK - 1) & ~(CHUNK - 1);
        }
        *(int4*)(off + base + 4 * i) = make_int4(o[0], o[1], o[2], o[3]);
        *(int4*)(cur + base + 4 * i) = make_int4(o[0], o[1], o[2], o[3]);
        *(float4*)(inv + base + 4 * i) = make_float4(iv[0], iv[1], iv[2], iv[3]);
    }
    if (tid == T - 1) off[N] = run;
}

// Per-(edge,bucket) cursors from padded edge offsets + bucket counts.
__global__ void bucket_cursors(const int* __restrict__ off_e,
                               const int* __restrict__ deg_eb,
                               int* __restrict__ cur_eb, int E) {
    int e = blockIdx.x * 256 + threadIdx.x;
    if (e < E) {
        int base = off_e[e];
#pragma unroll
        for (int b = 0; b < 8; ++b) {
            cur_eb[e * 8 + b] = base;
            base += deg_eb[e * 8 + b];
        }
    }
}

// Fill padded slots with dummy row indices; zero the dummy rows of xs8/es8.
__global__ void init_pad(int* __restrict__ nbrE, int nE, int dummyE,
                         int* __restrict__ nbrV, int nV, int dummyV,
                         unsigned* __restrict__ x8zero, unsigned* __restrict__ e8zero) {
    int i = blockIdx.x * 256 + threadIdx.x;
    if (i < nE) nbrE[i] = dummyE;
    if (i < nV) nbrV[i] = dummyV;
    if (i < 32) { x8zero[i] = 0u; e8zero[i] = 0u; }  // 128B fp8 dummy rows
}

// Bucketed fill: edge member lists land sorted by vertex bucket.
__global__ void fill_csr(const int* __restrict__ vids, const int* __restrict__ eids,
                         int* __restrict__ cur_v, int* __restrict__ cur_eb,
                         int* __restrict__ v_nbr_e, int* __restrict__ e_nbr_v, int nnz) {
    int n = blockIdx.x * blockDim.x + threadIdx.x;
    if (n < nnz) {
        int v = vids[n], e = eids[n];
        int p = atomicAdd(&cur_eb[e * 8 + (v >> 13)], 1);
        e_nbr_v[p] = v;
        int q = atomicAdd(&cur_v[v], 1);
        v_nbr_e[q] = e;
    }
}

// ---------------- per-segment gather bodies (R8 shapes) ----------------

__device__ __forceinline__ void seg_v2e(int seg, int lane,
                                        const unsigned short* __restrict__ xs8,
                                        const int* __restrict__ offs,
                                        const int* __restrict__ nbr,
                                        const float* __restrict__ inv_e,
                                        unsigned short* __restrict__ es8) {
    int p = offs[seg], pend = offs[seg + 1];
    float ax = 0.f, ay = 0.f;
    for (; p < pend; p += 8) {
        int4 c0 = *(const int4*)(nbr + p);
        int4 c1 = *(const int4*)(nbr + p + 4);
        unsigned r0 = xs8[(size_t)c0.x * 64 + lane];
        unsigned r1 = xs8[(size_t)c0.y * 64 + lane];
        unsigned r2 = xs8[(size_t)c0.z * 64 + lane];
        unsigned r3 = xs8[(size_t)c0.w * 64 + lane];
        unsigned r4 = xs8[(size_t)c1.x * 64 + lane];
        unsigned r5 = xs8[(size_t)c1.y * 64 + lane];
        unsigned r6 = xs8[(size_t)c1.z * 64 + lane];
        unsigned r7 = xs8[(size_t)c1.w * 64 + lane];
        float a, b;
        fp8x2_to_f32(r0, a, b); ax += a; ay += b;
        fp8x2_to_f32(r1, a, b); ax += a; ay += b;
        fp8x2_to_f32(r2, a, b); ax += a; ay += b;
        fp8x2_to_f32(r3, a, b); ax += a; ay += b;
        fp8x2_to_f32(r4, a, b); ax += a; ay += b;
        fp8x2_to_f32(r5, a, b); ax += a; ay += b;
        fp8x2_to_f32(r6, a, b); ax += a; ay += b;
        fp8x2_to_f32(r7, a, b); ax += a; ay += b;
    }
    float sc = inv_e[seg];
    es8[(size_t)seg * 64 + lane] = (unsigned short)f32_to_fp8x2(ax * sc, ay * sc);
}

__device__ __forceinline__ void seg_e2v(int seg, int lane,
                                        const unsigned short* __restrict__ es8,
                                        const int* __restrict__ offs,
                                        const int* __restrict__ nbr,
                                        const float* __restrict__ inv_v,
                                        unsigned short* __restrict__ xs8,
                                        unsigned* __restrict__ ck) {
    int p = offs[seg], pend = offs[seg + 1];
    float ax = 0.f, ay = 0.f;
    for (; p < pend; p += 4) {
        int4 c = *(const int4*)(nbr + p);
        unsigned r0 = es8[(size_t)c.x * 64 + lane];
        unsigned r1 = es8[(size_t)c.y * 64 + lane];
        unsigned r2 = es8[(size_t)c.z * 64 + lane];
        unsigned r3 = es8[(size_t)c.w * 64 + lane];
        float a, b;
        fp8x2_to_f32(r0, a, b); ax += a; ay += b;
        fp8x2_to_f32(r1, a, b); ax += a; ay += b;
        fp8x2_to_f32(r2, a, b); ax += a; ay += b;
        fp8x2_to_f32(r3, a, b); ax += a; ay += b;
    }
    float sc = inv_v[seg];
    float xl = ax * sc, xh = ay * sc;
    xs8[(size_t)seg * 64 + lane] = (unsigned short)f32_to_fp8x2(xl, xh);
    if (ck) ck[(size_t)seg * 1536 + lane] = hpack(xl, xh);
}

// ---------------- cooperative fused 16-step diffusion ----------------

__global__ __launch_bounds__(256, 4) void diffuse16(
    const float* __restrict__ X, const float* __restrict__ inv_v,
    const float* __restrict__ inv_e,
    unsigned short* __restrict__ xs8, unsigned short* __restrict__ es8,
    const int* __restrict__ off_e, const int* __restrict__ e_nbr_v,
    const int* __restrict__ off_v, const int* __restrict__ v_nbr_e,
    unsigned* __restrict__ out_u, int V, int E) {
    cg::grid_group grid = cg::this_grid();
    int tid = blockIdx.x * 256 + threadIdx.x;
    int nthr = gridDim.x * 256;
    int lane = threadIdx.x & 63;
    int wv0 = __builtin_amdgcn_readfirstlane(tid >> 6);
    int nw = nthr >> 6;

    // phase 0: xs8 = fp8(X * inv_v)
    for (int i = tid; i < V * 32; i += nthr) {
        int v = i >> 5, d = i & 31;
        float sc = inv_v[v];
        float4 x = *(const float4*)(X + (size_t)v * FEAT + 4 * d);
        unsigned lo = f32_to_fp8x2(x.x * sc, x.y * sc);
        unsigned hi = f32_to_fp8x2(x.z * sc, x.w * sc);
        ((unsigned*)xs8)[(size_t)v * 32 + d] = lo | (hi << 16);
    }
    grid.sync();

    for (int k = 1; k <= 16; ++k) {
        for (int seg = wv0; seg < E; seg += nw) {
            int s = __builtin_amdgcn_readfirstlane(seg);
            seg_v2e(s, lane, xs8, off_e, e_nbr_v, inv_e, es8);
        }
        grid.sync();
        unsigned* ck = nullptr;
        if (k == 1) ck = out_u + 1 * 256;
        else if (k == 2) ck = out_u + 2 * 256;
        else if (k == 4) ck = out_u + 3 * 256;
        else if (k == 8) ck = out_u + 4 * 256;
        else if (k == 16) ck = out_u + 5 * 256;
        for (int seg = wv0; seg < V; seg += nw) {
            int s = __builtin_amdgcn_readfirstlane(seg);
            seg_e2v(s, lane, es8, off_v, v_nbr_e, inv_v, xs8, ck);
        }
        grid.sync();
    }
}

// ---------------- fallback dispatch-loop kernels ----------------

__global__ __launch_bounds__(256) void prescale(const float* __restrict__ X,
                                                const float* __restrict__ inv_v,
                                                unsigned* __restrict__ xs8) {
    int tid = blockIdx.x * 256 + threadIdx.x;
    int v = tid >> 5, d = tid & 31;
    float sc = inv_v[v];
    float4 x = *(const float4*)(X + (size_t)v * FEAT + 4 * d);
    unsigned lo = f32_to_fp8x2(x.x * sc, x.y * sc);
    unsigned hi = f32_to_fp8x2(x.z * sc, x.w * sc);
    xs8[(size_t)v * 32 + d] = lo | (hi << 16);
}

__global__ __launch_bounds__(256) void k_v2e(const unsigned short* __restrict__ xs8,
                                             const int* __restrict__ offs,
                                             const int* __restrict__ nbr,
                                             const float* __restrict__ inv_e,
                                             unsigned short* __restrict__ es8, int nseg) {
    int seg = __builtin_amdgcn_readfirstlane(blockIdx.x * 4 + (threadIdx.x >> 6));
    if (seg < nseg)
        seg_v2e(seg, threadIdx.x & 63, xs8, offs, nbr, inv_e, es8);
}

__global__ __launch_bounds__(256) void k_e2v(const unsigned short* __restrict__ es8,
                                             const int* __restrict__ offs,
                                             const int* __restrict__ nbr,
                                             const float* __restrict__ inv_v,
                                             unsigned short* __restrict__ xs8,
                                             unsigned* __restrict__ ck, int nseg) {
    int seg0 = __builtin_amdgcn_readfirstlane(blockIdx.x * 4 + (threadIdx.x >> 6)) * 4;
    if (seg0 >= nseg) return;
    int lane = threadIdx.x & 63;
#pragma unroll
    for (int i = 0; i < 4; ++i)
        seg_e2v(seg0 + i, lane, es8, offs, nbr, inv_v, xs8, ck);
}

// ---------------- final wavelet combine + relu split ----------------

__global__ __launch_bounds__(256) void wavelet_out(const float* __restrict__ X,
                                                   const int* __restrict__ deg_v,
                                                   float* __restrict__ out) {
    int tid = blockIdx.x * 256 + threadIdx.x;
    int v = tid >> 5;
    int f4 = (tid & 31) * 4;
    float* row = out + (size_t)v * 1536;
    const unsigned* rowu = (const unsigned*)row;
    float degf = (float)deg_v[v];
    float4 L0v = *(const float4*)(X + (size_t)v * FEAT + f4);
    float l0[4] = {L0v.x, L0v.y, L0v.z, L0v.w};
    float L[5][4];
#pragma unroll
    for (int s = 0; s < 5; ++s) {
        unsigned d0 = rowu[(s + 1) * 256 + (f4 >> 1)];
        unsigned d1 = rowu[(s + 1) * 256 + (f4 >> 1) + 1];
        L[s][0] = hlo(d0) * degf;
        L[s][1] = hhi(d0) * degf;
        L[s][2] = hlo(d1) * degf;
        L[s][3] = hhi(d1) * degf;
    }
    float wv[6][4];
#pragma unroll
    for (int j = 0; j < 4; ++j) {
        wv[0][j] = l0[j] - L[0][j];
        wv[1][j] = L[0][j] - L[1][j];
        wv[2][j] = L[1][j] - L[2][j];
        wv[3][j] = L[2][j] - L[3][j];
        wv[4][j] = L[3][j] - L[4][j];
        wv[5][j] = L[4][j];
    }
    __syncthreads();
#pragma unroll
    for (int r = 0; r < 6; ++r) {
        float4 pp, mm;
        pp.x = fmaxf(wv[r][0], 0.f); mm.x = fmaxf(-wv[r][0], 0.f);
        pp.y = fmaxf(wv[r][1], 0.f); mm.y = fmaxf(-wv[r][1], 0.f);
        pp.z = fmaxf(wv[r][2], 0.f); mm.z = fmaxf(-wv[r][2], 0.f);
        pp.w = fmaxf(wv[r][3], 0.f); mm.w = fmaxf(-wv[r][3], 0.f);
        *(float4*)(row + r * 256 + f4) = pp;
        *(float4*)(row + r * 256 + 128 + f4) = mm;
    }
}

// ---------------- launch ----------------

extern "C" void kernel_launch(void* const* d_in, const int* in_sizes, int n_in,
                              void* d_out, int out_size, void* d_ws, size_t ws_size,
                              hipStream_t stream) {
    const float* X = (const float*)d_in[0];
    const int* vids = (const int*)d_in[1];
    const int* eids = (const int*)d_in[2];
    const int NNZ = in_sizes[1];       // 1048576
    const int V = in_sizes[0] / FEAT;  // 65536
    const int E = 16384;               // num_e
    float* out = (float*)d_out;
    unsigned* out_u = (unsigned*)d_out;

    const int NBRE_CAP = NNZ + E * 8;  // edge lists, CHUNK=8 padding
    const int NBRV_CAP = NNZ + V * 4;  // vertex lists, CHUNK=4 padding

    char* w = (char*)d_ws;
    size_t o = 0;
    auto take = [&](size_t bytes) {
        void* p = (void*)(w + o);
        o = (o + bytes + 255) & ~(size_t)255;
        return p;
    };
    int* deg_v = (int*)take((size_t)(V + E + E * 8) * 4);  // deg_v, deg_e, deg_eb contiguous
    int* deg_e = deg_v + V;
    int* deg_eb = deg_e + E;
    int* off_e = (int*)take((size_t)(E + 1) * 4);
    int* off_v = (int*)take((size_t)(V + 1) * 4);
    int* cur_e = (int*)take((size_t)E * 4);
    int* cur_v = (int*)take((size_t)V * 4);
    int* cur_eb = (int*)take((size_t)E * 8 * 4);
    float* inv_e = (float*)take((size_t)E * 4);
    float* inv_v = (float*)take((size_t)V * 4);
    int* e_nbr_v = (int*)take((size_t)NBRE_CAP * 4);
    int* v_nbr_e = (int*)take((size_t)NBRV_CAP * 4);
    unsigned* xs8 = (unsigned*)take((size_t)(V + 1) * 32 * 4);  // fp8 [V+1][128]
    unsigned* es8 = (unsigned*)take((size_t)(E + 1) * 32 * 4);  // fp8 [E+1][128]
    (void)ws_size;
    (void)n_in;
    (void)out_size;

    // 1) degrees (+ per-bucket edge degrees)
    hipMemsetAsync(deg_v, 0, (size_t)(V + E + E * 8) * 4, stream);
    count_deg<<<(NNZ + 255) / 256, 256, 0, stream>>>(vids, eids, deg_v, deg_e, deg_eb, NNZ);

    // 2) padded offsets + cursors + 1/true-degree
    scan_pad<16384, 1024, 8><<<1, 1024, 0, stream>>>(deg_e, off_e, cur_e, inv_e);
    scan_pad<65536, 1024, 4><<<1, 1024, 0, stream>>>(deg_v, off_v, cur_v, inv_v);
    bucket_cursors<<<(E + 255) / 256, 256, 0, stream>>>(off_e, deg_eb, cur_eb, E);

    // 3) dummy-fill padded lists (dummy -> zero row), zero dummy rows
    {
        int mx = NBRV_CAP > NBRE_CAP ? NBRV_CAP : NBRE_CAP;
        init_pad<<<(mx + 255) / 256, 256, 0, stream>>>(e_nbr_v, NBRE_CAP, V,
                                                       v_nbr_e, NBRV_CAP, E,
                                                       xs8 + (size_t)V * 32,
                                                       es8 + (size_t)E * 32);
    }

    // 4) adjacency lists (edge members bucket-sorted by vertex range)
    fill_csr<<<(NNZ + 255) / 256, 256, 0, stream>>>(vids, eids, cur_v, cur_eb,
                                                    v_nbr_e, e_nbr_v, NNZ);

    // 5) fused prescale + 16 diffusion steps via cooperative persistent waves;
    //    fallback to per-step dispatches if cooperative launch unavailable.
    bool coop_done = false;
    {
        int mb = 0;
        hipError_t qe =
            hipOccupancyMaxActiveBlocksPerMultiprocessor(&mb, (const void*)diffuse16, 256, 0);
        if (qe != hipSuccess || mb < 1) mb = 2;
        if (mb > 8) mb = 8;
        int grid = mb * 256;  // 256 CUs on MI355X
        int Vv = V, Ev = E;
        unsigned short* xs8s = (unsigned short*)xs8;
        unsigned short* es8s = (unsigned short*)es8;
        void* args[] = {(void*)&X,      (void*)&inv_v,   (void*)&inv_e, (void*)&xs8s,
                        (void*)&es8s,   (void*)&off_e,   (void*)&e_nbr_v,
                        (void*)&off_v,  (void*)&v_nbr_e, (void*)&out_u, (void*)&Vv,
                        (void*)&Ev};
        hipError_t le = hipLaunchCooperativeKernel((void*)diffuse16, dim3(grid), dim3(256),
                                                   args, 0, stream);
        coop_done = (le == hipSuccess);
    }
    if (!coop_done) {
        prescale<<<V * 32 / 256, 256, 0, stream>>>(X, inv_v, xs8);
        for (int k = 1; k <= 16; ++k) {
            k_v2e<<<E / 4, 256, 0, stream>>>((const unsigned short*)xs8, off_e, e_nbr_v,
                                             inv_e, (unsigned short*)es8, E);
            unsigned* ck = nullptr;
            if (k == 1) ck = out_u + 1 * 256;
            else if (k == 2) ck = out_u + 2 * 256;
            else if (k == 4) ck = out_u + 3 * 256;
            else if (k == 8) ck = out_u + 4 * 256;
            else if (k == 16) ck = out_u + 5 * 256;
            k_e2v<<<V / 16, 256, 0, stream>>>((const unsigned short*)es8, off_v, v_nbr_e,
                                              inv_v, (unsigned short*)xs8, ck, V);
        }
    }

    // 6) wavelet combine + relu split, in place over out
    wavelet_out<<<V * 32 / 256, 256, 0, stream>>>(X, deg_v, out);
}

// Round 12
// 1187.162 us; speedup vs baseline: 7.2941x; 7.2941x over previous
//
#include <hip/hip_runtime.h>
#include <hip/hip_fp16.h>

// HyperScatteringModule: V=65536, E=16384, NNZ=1048576, F=128
#define FEAT 128

typedef float f32x4 __attribute__((ext_vector_type(4)));

// ---------------- fp16 helpers ----------------

__device__ inline float hlo(unsigned u) {
    unsigned short s = (unsigned short)(u & 0xFFFFu);
    __half h = *(__half*)&s;
    return __half2float(h);
}
__device__ inline float hhi(unsigned u) {
    unsigned short s = (unsigned short)(u >> 16);
    __half h = *(__half*)&s;
    return __half2float(h);
}
__device__ inline unsigned hpack(float a, float b) {
    __half ha = __float2half_rn(a), hb = __float2half_rn(b);
    unsigned short ua = *(unsigned short*)&ha, ub = *(unsigned short*)&hb;
    return (unsigned)ua | ((unsigned)ub << 16);
}

// ---------------- fp8 e4m3 helpers ----------------
#if __has_builtin(__builtin_amdgcn_cvt_pk_f32_fp8) && __has_builtin(__builtin_amdgcn_cvt_pk_fp8_f32)
typedef float floatx2 __attribute__((ext_vector_type(2)));
__device__ inline void fp8x2_to_f32(unsigned lo16, float& a, float& b) {
    floatx2 r = __builtin_amdgcn_cvt_pk_f32_fp8((int)lo16, false);
    a = r.x;
    b = r.y;
}
__device__ inline unsigned f32_to_fp8x2(float a, float b) {
    return (unsigned)__builtin_amdgcn_cvt_pk_fp8_f32(a, b, 0, false) & 0xFFFFu;
}
#else
__device__ inline float fp8_dec1(unsigned u) {
    unsigned s = (u >> 7) & 1u, e = (u >> 3) & 15u, m = u & 7u;
    float v;
    if (e != 0) {
        unsigned bits = (s << 31) | ((e + 120u) << 23) | (m << 20);
        v = __uint_as_float(bits);
    } else {
        v = (float)m * 0.001953125f;
        if (s) v = -v;
    }
    return v;
}
__device__ inline void fp8x2_to_f32(unsigned lo16, float& a, float& b) {
    a = fp8_dec1(lo16 & 0xFFu);
    b = fp8_dec1((lo16 >> 8) & 0xFFu);
}
__device__ inline unsigned fp8_enc1(float x) {
    float ax = fabsf(x);
    unsigned s = (__float_as_uint(x) >> 31) << 7;
    if (ax >= 448.f) return s | 0x7Eu;
    if (ax < 0.0009765625f) return s;
    if (ax < 0.015625f) {
        unsigned m = (unsigned)__builtin_rintf(ax * 512.f);
        if (m > 7u) m = 7u;
        return s | m;
    }
    unsigned bits = __float_as_uint(ax);
    int e32 = (int)((bits >> 23) & 255u) - 127;
    unsigned mant = bits & 0x7FFFFFu;
    unsigned m3 = mant >> 20;
    unsigned rem = mant & 0xFFFFFu;
    if (rem > 0x80000u || (rem == 0x80000u && (m3 & 1u))) {
        m3++;
        if (m3 == 8u) { m3 = 0; e32++; }
    }
    if (e32 > 8) return s | 0x7Eu;
    return s | ((unsigned)(e32 + 7) << 3) | m3;
}
__device__ inline unsigned f32_to_fp8x2(float a, float b) {
    return fp8_enc1(a) | (fp8_enc1(b) << 8);
}
#endif

// ---------------- CSR build ----------------

// deg_v + per-(edge,bucket) counts only (deg_e derived in scan).
__global__ void count_deg(const int* __restrict__ vids, const int* __restrict__ eids,
                          int* __restrict__ deg_v, int* __restrict__ deg_eb, int nnz) {
    int n = blockIdx.x * blockDim.x + threadIdx.x;
    if (n < nnz) {
        int v = vids[n], e = eids[n];
        atomicAdd(&deg_v[v], 1);
        atomicAdd(&deg_eb[e * 8 + (v >> 13)], 1);  // 8 vertex-buckets of 8192
    }
}

// One kernel, two blocks: block 0 scans edges (CHUNK=8, bucket cursors),
// block 1 scans vertices (CHUNK=4). Each also dummy-pads its list tails and
// zeroes its dummy feature row.
__global__ __launch_bounds__(1024) void scan_both(
    const int* __restrict__ deg_v, const int* __restrict__ deg_eb,
    int* __restrict__ off_e, int* __restrict__ cur_eb, float* __restrict__ inv_e,
    int* __restrict__ e_nbr_v,
    int* __restrict__ off_v, int* __restrict__ cur_v, float* __restrict__ inv_v,
    int* __restrict__ v_nbr_e,
    unsigned* __restrict__ xs8d, unsigned* __restrict__ es8d, int V, int E) {
    __shared__ int partial[1024];
    int tid = threadIdx.x;
    if (blockIdx.x == 0) {
        // edges: E=16384, per=16, pad to multiple of 8
        const int per = 16;
        int base = tid * per;
        int degs[per];
        int s = 0;
#pragma unroll
        for (int i = 0; i < per; ++i) {
            int d = 0;
#pragma unroll
            for (int b = 0; b < 8; ++b) d += deg_eb[(base + i) * 8 + b];
            degs[i] = d;
            s += (d + 7) & ~7;
        }
        partial[tid] = s;
        __syncthreads();
        for (int dd = 1; dd < 1024; dd <<= 1) {
            int add = (tid >= dd) ? partial[tid - dd] : 0;
            __syncthreads();
            partial[tid] += add;
            __syncthreads();
        }
        int run = (tid > 0) ? partial[tid - 1] : 0;
#pragma unroll
        for (int i = 0; i < per; ++i) {
            int e = base + i, d = degs[i];
            off_e[e] = run;
            inv_e[e] = (d > 0) ? (1.0f / (float)d) : 0.0f;
            int b0 = run;
#pragma unroll
            for (int b = 0; b < 8; ++b) {
                cur_eb[e * 8 + b] = b0;
                b0 += deg_eb[e * 8 + b];
            }
            int pad = (d + 7) & ~7;
            for (int j = d; j < pad; ++j) e_nbr_v[run + j] = V;  // dummy vertex
            run += pad;
        }
        if (tid == 1023) off_e[E] = run;
        if (tid < 32) es8d[(size_t)E * 32 + tid] = 0u;
    } else {
        // vertices: V=65536, per=64, pad to multiple of 4
        const int per = 64;
        int base = tid * per;
        int s = 0;
        for (int i = 0; i < per; i += 4) {
            int4 d4 = *(const int4*)(deg_v + base + i);
            s += ((d4.x + 3) & ~3) + ((d4.y + 3) & ~3) + ((d4.z + 3) & ~3) +
                 ((d4.w + 3) & ~3);
        }
        partial[tid] = s;
        __syncthreads();
        for (int dd = 1; dd < 1024; dd <<= 1) {
            int add = (tid >= dd) ? partial[tid - dd] : 0;
            __syncthreads();
            partial[tid] += add;
            __syncthreads();
        }
        int run = (tid > 0) ? partial[tid - 1] : 0;
        for (int i = 0; i < per; ++i) {
            int v = base + i;
            int d = deg_v[v];
            off_v[v] = run;
            cur_v[v] = run;
            inv_v[v] = (d > 0) ? (1.0f / (float)d) : 0.0f;
            int pad = (d + 3) & ~3;
            for (int j = d; j < pad; ++j) v_nbr_e[run + j] = E;  // dummy edge
            run += pad;
        }
        if (tid == 1023) off_v[V] = run;
        if (tid < 32) xs8d[(size_t)V * 32 + tid] = 0u;
    }
}

// Bucketed fill: edge member lists land sorted by vertex bucket (ascending locality).
__global__ void fill_csr(const int* __restrict__ vids, const int* __restrict__ eids,
                         int* __restrict__ cur_v, int* __restrict__ cur_eb,
                         int* __restrict__ v_nbr_e, int* __restrict__ e_nbr_v, int nnz) {
    int n = blockIdx.x * blockDim.x + threadIdx.x;
    if (n < nnz) {
        int v = vids[n], e = eids[n];
        int p = atomicAdd(&cur_eb[e * 8 + (v >> 13)], 1);
        e_nbr_v[p] = v;
        int q = atomicAdd(&cur_v[v], 1);
        v_nbr_e[q] = e;
    }
}

// ---------------- prescale: xs8[v] = fp8(X[v] * inv_v), 4 feats/thread ----------------
__global__ __launch_bounds__(256) void prescale(const float* __restrict__ X,
                                                const float* __restrict__ inv_v,
                                                unsigned* __restrict__ xs8) {
    int tid = blockIdx.x * 256 + threadIdx.x;  // over V*32 dwords
    int v = tid >> 5, d = tid & 31;
    float sc = inv_v[v];
    float4 x = *(const float4*)(X + (size_t)v * FEAT + 4 * d);
    unsigned lo = f32_to_fp8x2(x.x * sc, x.y * sc);
    unsigned hi = f32_to_fp8x2(x.z * sc, x.w * sc);
    xs8[(size_t)v * 32 + d] = lo | (hi << 16);
}

// ---------------- v2e gather: fp8 xs rows -> fp32 acc -> fp8 es (R8 shape) ----------------
__global__ __launch_bounds__(256) void k_v2e(const unsigned short* __restrict__ xs8,
                                             const int* __restrict__ offs,
                                             const int* __restrict__ nbr,
                                             const float* __restrict__ inv_e,
                                             unsigned short* __restrict__ es8, int nseg) {
    int seg = __builtin_amdgcn_readfirstlane(blockIdx.x * 4 + (threadIdx.x >> 6));
    if (seg >= nseg) return;
    int lane = threadIdx.x & 63;
    int p = offs[seg], pend = offs[seg + 1];
    float ax = 0.f, ay = 0.f;
    for (; p < pend; p += 8) {
        int4 c0 = *(const int4*)(nbr + p);
        int4 c1 = *(const int4*)(nbr + p + 4);
        unsigned r0 = xs8[(size_t)c0.x * 64 + lane];
        unsigned r1 = xs8[(size_t)c0.y * 64 + lane];
        unsigned r2 = xs8[(size_t)c0.z * 64 + lane];
        unsigned r3 = xs8[(size_t)c0.w * 64 + lane];
        unsigned r4 = xs8[(size_t)c1.x * 64 + lane];
        unsigned r5 = xs8[(size_t)c1.y * 64 + lane];
        unsigned r6 = xs8[(size_t)c1.z * 64 + lane];
        unsigned r7 = xs8[(size_t)c1.w * 64 + lane];
        float a, b;
        fp8x2_to_f32(r0, a, b); ax += a; ay += b;
        fp8x2_to_f32(r1, a, b); ax += a; ay += b;
        fp8x2_to_f32(r2, a, b); ax += a; ay += b;
        fp8x2_to_f32(r3, a, b); ax += a; ay += b;
        fp8x2_to_f32(r4, a, b); ax += a; ay += b;
        fp8x2_to_f32(r5, a, b); ax += a; ay += b;
        fp8x2_to_f32(r6, a, b); ax += a; ay += b;
        fp8x2_to_f32(r7, a, b); ax += a; ay += b;
    }
    float sc = inv_e[seg];
    es8[(size_t)seg * 64 + lane] = (unsigned short)f32_to_fp8x2(ax * sc, ay * sc);
}

// ---------------- e2v gather: fp8 es rows -> fp32 acc -> fp8 xs + NT fp16 ckpt ----------------
__global__ __launch_bounds__(256) void k_e2v(const unsigned short* __restrict__ es8,
                                             const int* __restrict__ offs,
                                             const int* __restrict__ nbr,
                                             const float* __restrict__ inv_v,
                                             unsigned short* __restrict__ xs8,
                                             unsigned* __restrict__ ckpt, int nseg) {
    int wv = __builtin_amdgcn_readfirstlane(blockIdx.x * 4 + (threadIdx.x >> 6));
    int lane = threadIdx.x & 63;
    int seg0 = wv * 4;
    if (seg0 >= nseg) return;
    int p = offs[seg0];
#pragma unroll
    for (int i = 0; i < 4; ++i) {
        int s = seg0 + i;
        int pend = offs[s + 1];
        float ax = 0.f, ay = 0.f;
        for (; p < pend; p += 4) {
            int4 c = *(const int4*)(nbr + p);
            unsigned r0 = es8[(size_t)c.x * 64 + lane];
            unsigned r1 = es8[(size_t)c.y * 64 + lane];
            unsigned r2 = es8[(size_t)c.z * 64 + lane];
            unsigned r3 = es8[(size_t)c.w * 64 + lane];
            float a, b;
            fp8x2_to_f32(r0, a, b); ax += a; ay += b;
            fp8x2_to_f32(r1, a, b); ax += a; ay += b;
            fp8x2_to_f32(r2, a, b); ax += a; ay += b;
            fp8x2_to_f32(r3, a, b); ax += a; ay += b;
        }
        float sc = inv_v[s];
        float xl = ax * sc, xh = ay * sc;
        xs8[(size_t)s * 64 + lane] = (unsigned short)f32_to_fp8x2(xl, xh);
        if (ckpt)
            __builtin_nontemporal_store(hpack(xl, xh), &ckpt[(size_t)s * 1536 + lane]);
    }
}

// ---------------- final wavelet combine + relu split ----------------
// Checkpoints: fp16(inv_v*L) at out dwords v*1536 + slot*256 + [0,64).
// Recover L = ckpt * deg_v. 256 threads = 8 vertices, 4 feats/thread.
__global__ __launch_bounds__(256) void wavelet_out(const float* __restrict__ X,
                                                   const int* __restrict__ deg_v,
                                                   float* __restrict__ out) {
    int tid = blockIdx.x * 256 + threadIdx.x;
    int v = tid >> 5;
    int f4 = (tid & 31) * 4;
    float* row = out + (size_t)v * 1536;
    const unsigned* rowu = (const unsigned*)row;
    float degf = (float)deg_v[v];
    float4 L0v = *(const float4*)(X + (size_t)v * FEAT + f4);
    float l0[4] = {L0v.x, L0v.y, L0v.z, L0v.w};
    float L[5][4];
#pragma unroll
    for (int s = 0; s < 5; ++s) {
        unsigned d0 = rowu[(s + 1) * 256 + (f4 >> 1)];
        unsigned d1 = rowu[(s + 1) * 256 + (f4 >> 1) + 1];
        L[s][0] = hlo(d0) * degf;
        L[s][1] = hhi(d0) * degf;
        L[s][2] = hlo(d1) * degf;
        L[s][3] = hhi(d1) * degf;
    }
    float wv[6][4];
#pragma unroll
    for (int j = 0; j < 4; ++j) {
        wv[0][j] = l0[j] - L[0][j];
        wv[1][j] = L[0][j] - L[1][j];
        wv[2][j] = L[1][j] - L[2][j];
        wv[3][j] = L[2][j] - L[3][j];
        wv[4][j] = L[3][j] - L[4][j];
        wv[5][j] = L[4][j];
    }
    __syncthreads();
#pragma unroll
    for (int r = 0; r < 6; ++r) {
        f32x4 pp, mm;
        pp.x = fmaxf(wv[r][0], 0.f); mm.x = fmaxf(-wv[r][0], 0.f);
        pp.y = fmaxf(wv[r][1], 0.f); mm.y = fmaxf(-wv[r][1], 0.f);
        pp.z = fmaxf(wv[r][2], 0.f); mm.z = fmaxf(-wv[r][2], 0.f);
        pp.w = fmaxf(wv[r][3], 0.f); mm.w = fmaxf(-wv[r][3], 0.f);
        __builtin_nontemporal_store(pp, (f32x4*)(row + r * 256 + f4));
        __builtin_nontemporal_store(mm, (f32x4*)(row + r * 256 + 128 + f4));
    }
}

// ---------------- launch ----------------

extern "C" void kernel_launch(void* const* d_in, const int* in_sizes, int n_in,
                              void* d_out, int out_size, void* d_ws, size_t ws_size,
                              hipStream_t stream) {
    const float* X = (const float*)d_in[0];
    const int* vids = (const int*)d_in[1];
    const int* eids = (const int*)d_in[2];
    const int NNZ = in_sizes[1];       // 1048576
    const int V = in_sizes[0] / FEAT;  // 65536
    const int E = 16384;               // num_e
    float* out = (float*)d_out;
    unsigned* out_u = (unsigned*)d_out;

    const int NBRE_CAP = NNZ + E * 8;  // edge lists, CHUNK=8 padding
    const int NBRV_CAP = NNZ + V * 4;  // vertex lists, CHUNK=4 padding

    char* w = (char*)d_ws;
    size_t o = 0;
    auto take = [&](size_t bytes) {
        void* p = (void*)(w + o);
        o = (o + bytes + 255) & ~(size_t)255;
        return p;
    };
    int* deg_v = (int*)take((size_t)(V + E * 8) * 4);  // deg_v, deg_eb contiguous
    int* deg_eb = deg_v + V;
    int* off_e = (int*)take((size_t)(E + 1) * 4);
    int* off_v = (int*)take((size_t)(V + 1) * 4);
    int* cur_eb = (int*)take((size_t)E * 8 * 4);
    int* cur_v = (int*)take((size_t)V * 4);
    float* inv_e = (float*)take((size_t)E * 4);
    float* inv_v = (float*)take((size_t)V * 4);
    int* e_nbr_v = (int*)take((size_t)NBRE_CAP * 4);
    int* v_nbr_e = (int*)take((size_t)NBRV_CAP * 4);
    unsigned* xs8 = (unsigned*)take((size_t)(V + 1) * 32 * 4);  // fp8 [V+1][128]
    unsigned* es8 = (unsigned*)take((size_t)(E + 1) * 32 * 4);  // fp8 [E+1][128]
    (void)ws_size;
    (void)n_in;
    (void)out_size;

    // 1) degrees (vertex + per-bucket edge)
    hipMemsetAsync(deg_v, 0, (size_t)(V + E * 8) * 4, stream);
    count_deg<<<(NNZ + 255) / 256, 256, 0, stream>>>(vids, eids, deg_v, deg_eb, NNZ);

    // 2) fused scans: offsets, cursors, 1/deg, tail padding, dummy-row zeroing
    scan_both<<<2, 1024, 0, stream>>>(deg_v, deg_eb, off_e, cur_eb, inv_e, e_nbr_v,
                                      off_v, cur_v, inv_v, v_nbr_e, xs8, es8, V, E);

    // 3) adjacency lists (edge members bucket-sorted by vertex range)
    fill_csr<<<(NNZ + 255) / 256, 256, 0, stream>>>(vids, eids, cur_v, cur_eb,
                                                    v_nbr_e, e_nbr_v, NNZ);

    // 4) xs8 = fp8(X * inv_v)
    prescale<<<V * 32 / 256, 256, 0, stream>>>(X, inv_v, xs8);

    // 5) 16 diffusion steps; checkpoints k in {1,2,4,8,16} write packed fp16
    //    scaled level into out[v, slot, dwords 0:64] (recovered by *deg_v).
    for (int k = 1; k <= 16; ++k) {
        k_v2e<<<E / 4, 256, 0, stream>>>((const unsigned short*)xs8, off_e, e_nbr_v,
                                         inv_e, (unsigned short*)es8, E);
        unsigned* ck = nullptr;
        if (k == 1) ck = out_u + 1 * 256;
        else if (k == 2) ck = out_u + 2 * 256;
        else if (k == 4) ck = out_u + 3 * 256;
        else if (k == 8) ck = out_u + 4 * 256;
        else if (k == 16) ck = out_u + 5 * 256;
        k_e2v<<<V / 16, 256, 0, stream>>>((const unsigned short*)es8, off_v, v_nbr_e,
                                          inv_v, (unsigned short*)xs8, ck, V);
    }

    // 6) wavelet combine + relu split, in place over out
    wavelet_out<<<V * 32 / 256, 256, 0, stream>>>(X, deg_v, out);
}

// Round 13
// 1069.293 us; speedup vs baseline: 8.0982x; 1.1102x over previous
//
#include <hip/hip_runtime.h>
#include <hip/hip_fp16.h>

// HyperScatteringModule: V=65536, E=16384, NNZ=1048576, F=128
#define FEAT 128

// ---------------- fp16 helpers ----------------

__device__ inline float hlo(unsigned u) {
    unsigned short s = (unsigned short)(u & 0xFFFFu);
    __half h = *(__half*)&s;
    return __half2float(h);
}
__device__ inline float hhi(unsigned u) {
    unsigned short s = (unsigned short)(u >> 16);
    __half h = *(__half*)&s;
    return __half2float(h);
}
__device__ inline unsigned hpack(float a, float b) {
    __half ha = __float2half_rn(a), hb = __float2half_rn(b);
    unsigned short ua = *(unsigned short*)&ha, ub = *(unsigned short*)&hb;
    return (unsigned)ua | ((unsigned)ub << 16);
}

// ---------------- fp8 e4m3 helpers ----------------
#if __has_builtin(__builtin_amdgcn_cvt_pk_f32_fp8) && __has_builtin(__builtin_amdgcn_cvt_pk_fp8_f32)
typedef float floatx2 __attribute__((ext_vector_type(2)));
__device__ inline void fp8x2_to_f32(unsigned lo16, float& a, float& b) {
    floatx2 r = __builtin_amdgcn_cvt_pk_f32_fp8((int)lo16, false);
    a = r.x;
    b = r.y;
}
__device__ inline unsigned f32_to_fp8x2(float a, float b) {
    return (unsigned)__builtin_amdgcn_cvt_pk_fp8_f32(a, b, 0, false) & 0xFFFFu;
}
#else
__device__ inline float fp8_dec1(unsigned u) {
    unsigned s = (u >> 7) & 1u, e = (u >> 3) & 15u, m = u & 7u;
    float v;
    if (e != 0) {
        unsigned bits = (s << 31) | ((e + 120u) << 23) | (m << 20);
        v = __uint_as_float(bits);
    } else {
        v = (float)m * 0.001953125f;
        if (s) v = -v;
    }
    return v;
}
__device__ inline void fp8x2_to_f32(unsigned lo16, float& a, float& b) {
    a = fp8_dec1(lo16 & 0xFFu);
    b = fp8_dec1((lo16 >> 8) & 0xFFu);
}
__device__ inline unsigned fp8_enc1(float x) {
    float ax = fabsf(x);
    unsigned s = (__float_as_uint(x) >> 31) << 7;
    if (ax >= 448.f) return s | 0x7Eu;
    if (ax < 0.0009765625f) return s;
    if (ax < 0.015625f) {
        unsigned m = (unsigned)__builtin_rintf(ax * 512.f);
        if (m > 7u) m = 7u;
        return s | m;
    }
    unsigned bits = __float_as_uint(ax);
    int e32 = (int)((bits >> 23) & 255u) - 127;
    unsigned mant = bits & 0x7FFFFFu;
    unsigned m3 = mant >> 20;
    unsigned rem = mant & 0xFFFFFu;
    if (rem > 0x80000u || (rem == 0x80000u && (m3 & 1u))) {
        m3++;
        if (m3 == 8u) { m3 = 0; e32++; }
    }
    if (e32 > 8) return s | 0x7Eu;
    return s | ((unsigned)(e32 + 7) << 3) | m3;
}
__device__ inline unsigned f32_to_fp8x2(float a, float b) {
    return fp8_enc1(a) | (fp8_enc1(b) << 8);
}
#endif

// ---------------- CSR build ----------------

__global__ void count_deg(const int* __restrict__ vids, const int* __restrict__ eids,
                          int* __restrict__ deg_v, int* __restrict__ deg_e, int nnz) {
    int n = blockIdx.x * blockDim.x + threadIdx.x;
    if (n < nnz) {
        atomicAdd(&deg_v[vids[n]], 1);
        atomicAdd(&deg_e[eids[n]], 1);
    }
}

// Exclusive scan over CHUNK-padded degrees; off/cur = padded offsets, inv = 1/true_deg.
template <int N, int T, int CHUNK>
__global__ __launch_bounds__(T) void scan_pad(const int* __restrict__ deg,
                                              int* __restrict__ off,
                                              int* __restrict__ cur,
                                              float* __restrict__ inv) {
    __shared__ int partial[T];
    const int per = N / T;
    int tid = threadIdx.x;
    int base = tid * per;
    int dloc[per];
    int s = 0;
#pragma unroll
    for (int i = 0; i < per / 4; ++i) {
        int4 d4 = *(const int4*)(deg + base + 4 * i);
        dloc[4 * i] = d4.x; dloc[4 * i + 1] = d4.y;
        dloc[4 * i + 2] = d4.z; dloc[4 * i + 3] = d4.w;
        s += ((d4.x + CHUNK - 1) & ~(CHUNK - 1)) + ((d4.y + CHUNK - 1) & ~(CHUNK - 1)) +
             ((d4.z + CHUNK - 1) & ~(CHUNK - 1)) + ((d4.w + CHUNK - 1) & ~(CHUNK - 1));
    }
    partial[tid] = s;
    __syncthreads();
    for (int d = 1; d < T; d <<= 1) {
        int add = (tid >= d) ? partial[tid - d] : 0;
        __syncthreads();
        partial[tid] += add;
        __syncthreads();
    }
    int run = (tid > 0) ? partial[tid - 1] : 0;
#pragma unroll
    for (int i = 0; i < per / 4; ++i) {
        int o[4];
        float iv[4];
#pragma unroll
        for (int j = 0; j < 4; ++j) {
            int d = dloc[4 * i + j];
            o[j] = run;
            iv[j] = (d > 0) ? (1.0f / (float)d) : 0.0f;
            run += (d + CHUNK - 1) & ~(CHUNK - 1);
        }
        *(int4*)(off + base + 4 * i) = make_int4(o[0], o[1], o[2], o[3]);
        *(int4*)(cur + base + 4 * i) = make_int4(o[0], o[1], o[2], o[3]);
        *(float4*)(inv + base + 4 * i) = make_float4(iv[0], iv[1], iv[2], iv[3]);
    }
    if (tid == T - 1) off[N] = run;
}

// Fill padded slots with dummy row indices; zero the dummy rows of xs8/es8.
__global__ void init_pad(int* __restrict__ nbrE, int nE, int dummyE,
                         int* __restrict__ nbrV, int nV, int dummyV,
                         unsigned* __restrict__ x8zero, unsigned* __restrict__ e8zero) {
    int i = blockIdx.x * 256 + threadIdx.x;
    if (i < nE) nbrE[i] = dummyE;
    if (i < nV) nbrV[i] = dummyV;
    if (i < 32) { x8zero[i] = 0u; e8zero[i] = 0u; }  // 128B fp8 dummy rows
}

__global__ void fill_csr(const int* __restrict__ vids, const int* __restrict__ eids,
                         int* __restrict__ cur_v, int* __restrict__ cur_e,
                         int* __restrict__ v_nbr_e, int* __restrict__ e_nbr_v, int nnz) {
    int n = blockIdx.x * blockDim.x + threadIdx.x;
    if (n < nnz) {
        int v = vids[n], e = eids[n];
        int p = atomicAdd(&cur_e[e], 1);
        e_nbr_v[p] = v;
        int q = atomicAdd(&cur_v[v], 1);
        v_nbr_e[q] = e;
    }
}

// ---------------- prescale: xs8[v] = fp8(X[v] * inv_v), 4 feats/thread ----------------
__global__ __launch_bounds__(256) void prescale(const float* __restrict__ X,
                                                const float* __restrict__ inv_v,
                                                unsigned* __restrict__ xs8) {
    int tid = blockIdx.x * 256 + threadIdx.x;  // over V*32 dwords
    int v = tid >> 5, d = tid & 31;
    float sc = inv_v[v];
    float4 x = *(const float4*)(X + (size_t)v * FEAT + 4 * d);
    unsigned lo = f32_to_fp8x2(x.x * sc, x.y * sc);
    unsigned hi = f32_to_fp8x2(x.z * sc, x.w * sc);
    xs8[(size_t)v * 32 + d] = lo | (hi << 16);
}

// ---------------- v2e gather: fp8 xs rows -> fp32 acc -> fp8 es ----------------
// Wave per edge-segment (CHUNK=8 padded, dummy row = zeros). Lane owns 2 feats:
// loads ushort (2 fp8) at row*128B + lane*2; 1 VMEM (128B/wave) per visit.
__global__ __launch_bounds__(256) void gather_v2e(const unsigned short* __restrict__ xs8,
                                                  const int* __restrict__ offs,
                                                  const int* __restrict__ nbr,
                                                  const float* __restrict__ inv_e,
                                                  unsigned short* __restrict__ es8, int nseg) {
    int seg = __builtin_amdgcn_readfirstlane(blockIdx.x * 4 + (threadIdx.x >> 6));
    if (seg >= nseg) return;
    int lane = threadIdx.x & 63;
    int p = offs[seg], pend = offs[seg + 1];
    float ax = 0.f, ay = 0.f;
    for (; p < pend; p += 8) {
        int4 c0 = *(const int4*)(nbr + p);
        int4 c1 = *(const int4*)(nbr + p + 4);
        unsigned r0 = xs8[(size_t)c0.x * 64 + lane];
        unsigned r1 = xs8[(size_t)c0.y * 64 + lane];
        unsigned r2 = xs8[(size_t)c0.z * 64 + lane];
        unsigned r3 = xs8[(size_t)c0.w * 64 + lane];
        unsigned r4 = xs8[(size_t)c1.x * 64 + lane];
        unsigned r5 = xs8[(size_t)c1.y * 64 + lane];
        unsigned r6 = xs8[(size_t)c1.z * 64 + lane];
        unsigned r7 = xs8[(size_t)c1.w * 64 + lane];
        float a, b;
        fp8x2_to_f32(r0, a, b); ax += a; ay += b;
        fp8x2_to_f32(r1, a, b); ax += a; ay += b;
        fp8x2_to_f32(r2, a, b); ax += a; ay += b;
        fp8x2_to_f32(r3, a, b); ax += a; ay += b;
        fp8x2_to_f32(r4, a, b); ax += a; ay += b;
        fp8x2_to_f32(r5, a, b); ax += a; ay += b;
        fp8x2_to_f32(r6, a, b); ax += a; ay += b;
        fp8x2_to_f32(r7, a, b); ax += a; ay += b;
    }
    float sc = inv_e[seg];
    es8[(size_t)seg * 64 + lane] = (unsigned short)f32_to_fp8x2(ax * sc, ay * sc);
}

// ---------------- e2v gather: fp8 es rows -> fp32 acc -> fp8 xs + fp16 ckpt ----------------
// Wave handles 4 vertex-segments (CHUNK=4 padded, dummy row = zeros).
__global__ __launch_bounds__(256) void gather_e2v(const unsigned short* __restrict__ es8,
                                                  const int* __restrict__ offs,
                                                  const int* __restrict__ nbr,
                                                  const float* __restrict__ inv_v,
                                                  unsigned short* __restrict__ xs8,
                                                  unsigned* __restrict__ ckpt, int nseg) {
    int wv = __builtin_amdgcn_readfirstlane(blockIdx.x * 4 + (threadIdx.x >> 6));
    int lane = threadIdx.x & 63;
    int seg0 = wv * 4;
    if (seg0 >= nseg) return;
    int p = offs[seg0];
#pragma unroll
    for (int i = 0; i < 4; ++i) {
        int s = seg0 + i;
        int pend = offs[s + 1];
        float ax = 0.f, ay = 0.f;
        for (; p < pend; p += 4) {
            int4 c = *(const int4*)(nbr + p);
            unsigned r0 = es8[(size_t)c.x * 64 + lane];
            unsigned r1 = es8[(size_t)c.y * 64 + lane];
            unsigned r2 = es8[(size_t)c.z * 64 + lane];
            unsigned r3 = es8[(size_t)c.w * 64 + lane];
            float a, b;
            fp8x2_to_f32(r0, a, b); ax += a; ay += b;
            fp8x2_to_f32(r1, a, b); ax += a; ay += b;
            fp8x2_to_f32(r2, a, b); ax += a; ay += b;
            fp8x2_to_f32(r3, a, b); ax += a; ay += b;
        }
        float sc = inv_v[s];
        float xl = ax * sc, xh = ay * sc;
        xs8[(size_t)s * 64 + lane] = (unsigned short)f32_to_fp8x2(xl, xh);
        if (ckpt) ckpt[(size_t)s * 1536 + lane] = hpack(xl, xh);
    }
}

// ---------------- final wavelet combine + relu split ----------------
// Checkpoints: fp16(inv_v*L) at out dwords v*1536 + slot*256 + [0,64).
// Recover L = ckpt * deg_v. 256 threads = 8 vertices, 4 feats/thread.
__global__ __launch_bounds__(256) void wavelet_out(const float* __restrict__ X,
                                                   const int* __restrict__ deg_v,
                                                   float* __restrict__ out) {
    int tid = blockIdx.x * 256 + threadIdx.x;
    int v = tid >> 5;
    int f4 = (tid & 31) * 4;
    float* row = out + (size_t)v * 1536;
    const unsigned* rowu = (const unsigned*)row;
    float degf = (float)deg_v[v];
    float4 L0v = *(const float4*)(X + (size_t)v * FEAT + f4);
    float l0[4] = {L0v.x, L0v.y, L0v.z, L0v.w};
    float L[5][4];
#pragma unroll
    for (int s = 0; s < 5; ++s) {
        unsigned d0 = rowu[(s + 1) * 256 + (f4 >> 1)];
        unsigned d1 = rowu[(s + 1) * 256 + (f4 >> 1) + 1];
        L[s][0] = hlo(d0) * degf;
        L[s][1] = hhi(d0) * degf;
        L[s][2] = hlo(d1) * degf;
        L[s][3] = hhi(d1) * degf;
    }
    float wv[6][4];
#pragma unroll
    for (int j = 0; j < 4; ++j) {
        wv[0][j] = l0[j] - L[0][j];
        wv[1][j] = L[0][j] - L[1][j];
        wv[2][j] = L[1][j] - L[2][j];
        wv[3][j] = L[2][j] - L[3][j];
        wv[4][j] = L[3][j] - L[4][j];
        wv[5][j] = L[4][j];
    }
    __syncthreads();
#pragma unroll
    for (int r = 0; r < 6; ++r) {
        float4 pp, mm;
        pp.x = fmaxf(wv[r][0], 0.f); mm.x = fmaxf(-wv[r][0], 0.f);
        pp.y = fmaxf(wv[r][1], 0.f); mm.y = fmaxf(-wv[r][1], 0.f);
        pp.z = fmaxf(wv[r][2], 0.f); mm.z = fmaxf(-wv[r][2], 0.f);
        pp.w = fmaxf(wv[r][3], 0.f); mm.w = fmaxf(-wv[r][3], 0.f);
        *(float4*)(row + r * 256 + f4) = pp;
        *(float4*)(row + r * 256 + 128 + f4) = mm;
    }
}

// ---------------- launch ----------------

extern "C" void kernel_launch(void* const* d_in, const int* in_sizes, int n_in,
                              void* d_out, int out_size, void* d_ws, size_t ws_size,
                              hipStream_t stream) {
    const float* X = (const float*)d_in[0];
    const int* vids = (const int*)d_in[1];
    const int* eids = (const int*)d_in[2];
    const int NNZ = in_sizes[1];       // 1048576
    const int V = in_sizes[0] / FEAT;  // 65536
    const int E = 16384;               // num_e
    float* out = (float*)d_out;

    const int NBRE_CAP = NNZ + E * 8;  // edge lists, CHUNK=8 padding
    const int NBRV_CAP = NNZ + V * 4;  // vertex lists, CHUNK=4 padding

    char* w = (char*)d_ws;
    size_t o = 0;
    auto take = [&](size_t bytes) {
        void* p = (void*)(w + o);
        o = (o + bytes + 255) & ~(size_t)255;
        return p;
    };
    int* deg_v = (int*)take((size_t)(V + E) * 4);  // deg_v, deg_e contiguous
    int* deg_e = deg_v + V;
    int* off_e = (int*)take((size_t)(E + 1) * 4);
    int* off_v = (int*)take((size_t)(V + 1) * 4);
    int* cur_e = (int*)take((size_t)E * 4);
    int* cur_v = (int*)take((size_t)V * 4);
    float* inv_e = (float*)take((size_t)E * 4);
    float* inv_v = (float*)take((size_t)V * 4);
    int* e_nbr_v = (int*)take((size_t)NBRE_CAP * 4);            // edge segs -> vertex rows
    int* v_nbr_e = (int*)take((size_t)NBRV_CAP * 4);            // vertex segs -> edge rows
    unsigned* xs8 = (unsigned*)take((size_t)(V + 1) * 32 * 4);  // fp8 [V+1][128] = 8.4MB
    unsigned* es8 = (unsigned*)take((size_t)(E + 1) * 32 * 4);  // fp8 [E+1][128] = 2.1MB
    (void)ws_size;
    (void)n_in;
    (void)out_size;

    // 1) degrees
    hipMemsetAsync(deg_v, 0, (size_t)(V + E) * 4, stream);
    count_deg<<<(NNZ + 255) / 256, 256, 0, stream>>>(vids, eids, deg_v, deg_e, NNZ);

    // 2) padded offsets + cursors + 1/true-degree
    scan_pad<16384, 1024, 8><<<1, 1024, 0, stream>>>(deg_e, off_e, cur_e, inv_e);
    scan_pad<65536, 1024, 4><<<1, 1024, 0, stream>>>(deg_v, off_v, cur_v, inv_v);

    // 3) dummy-fill padded lists (dummy -> zero row), zero dummy rows
    {
        int mx = NBRV_CAP > NBRE_CAP ? NBRV_CAP : NBRE_CAP;
        init_pad<<<(mx + 255) / 256, 256, 0, stream>>>(e_nbr_v, NBRE_CAP, V,
                                                       v_nbr_e, NBRV_CAP, E,
                                                       xs8 + (size_t)V * 32,
                                                       es8 + (size_t)E * 32);
    }

    // 4) adjacency lists
    fill_csr<<<(NNZ + 255) / 256, 256, 0, stream>>>(vids, eids, cur_v, cur_e,
                                                    v_nbr_e, e_nbr_v, NNZ);

    // 5) xs8 = fp8(X * inv_v)
    prescale<<<V * 32 / 256, 256, 0, stream>>>(X, inv_v, xs8);

    // 6) 16 diffusion steps; checkpoints k in {1,2,4,8,16} also write packed
    //    fp16 scaled level into out[v, slot, dwords 0:64] (recovered by *deg_v).
    for (int k = 1; k <= 16; ++k) {
        gather_v2e<<<E / 4, 256, 0, stream>>>((const unsigned short*)xs8, off_e,
                                              e_nbr_v, inv_e, (unsigned short*)es8, E);
        unsigned* ck = nullptr;
        if (k == 1) ck = (unsigned*)out + 1 * 256;
        else if (k == 2) ck = (unsigned*)out + 2 * 256;
        else if (k == 4) ck = (unsigned*)out + 3 * 256;
        else if (k == 8) ck = (unsigned*)out + 4 * 256;
        else if (k == 16) ck = (unsigned*)out + 5 * 256;
        gather_e2v<<<V / 16, 256, 0, stream>>>((const unsigned short*)es8, off_v,
                                               v_nbr_e, inv_v, (unsigned short*)xs8, ck, V);
    }

    // 7) wavelet combine + relu split, in place over out
    wavelet_out<<<V * 32 / 256, 256, 0, stream>>>(X, deg_v, out);
}